// Round 7
// baseline (200.283 us; speedup 1.0000x reference)
//
#include <hip/hip_runtime.h>
#include <hip/hip_bf16.h>
#include <stdint.h>
#include <stddef.h>

#define B_ 8
#define S_ 2048
#define D_ 256
#define NROWS (B_ * S_)  // 16384

typedef __attribute__((ext_vector_type(8))) short short8;
typedef __attribute__((ext_vector_type(4))) short short4v;
typedef __attribute__((ext_vector_type(4))) float f32x4;

// round-to-nearest-even fp32 -> bf16 bit pattern
__device__ __forceinline__ short bf16of(float f) {
  union { float f; unsigned u; } x; x.f = f;
  unsigned r = x.u + 0x7FFFu + ((x.u >> 16) & 1u);
  return (short)(r >> 16);
}

// async global->LDS, 16B per lane (wave-uniform base + lane*16 layout)
__device__ __forceinline__ void async_ld16(const void* g, void* s) {
  __builtin_amdgcn_global_load_lds(
      (const __attribute__((address_space(1))) void*)g,
      (__attribute__((address_space(3))) void*)s, 16, 0, 0);
}

// Stage one 128x64 bf16 tile (1024 16B-slots, 8 slots/row) into LDS.
// LINEAR LDS dest; swizzle via permuted GLOBAL source (rule #21):
//   physical slot sp at row r holds logical slot sl = sp ^ (r&7).
// 4 issues per thread.
__device__ __forceinline__ void stage_tile64(const short* __restrict__ g_row0,
                                             char* lds_base, int t, int kk0) {
#pragma unroll
  for (int c = 0; c < 4; ++c) {
    int p = c * 256 + t;
    int r = p >> 3;
    int sl = (p & 7) ^ (r & 7);
    async_ld16(g_row0 + (size_t)r * D_ + kk0 + sl * 8, lds_base + p * 16);
  }
}

// ---------------- K0: UT[n][k] = bf16(U[k][n]) ----------------
__global__ void k_prep_u(const float* __restrict__ U, short* __restrict__ UT) {
  int n = blockIdx.x;
  int k = threadIdx.x;
  UT[n * D_ + k] = bf16of(U[k * D_ + n]);
}

// ---- K_rows: hs = head@wh, ds = dep@wd (fp32 exact); headB/depB = bf16(X) ----
__global__ void k_rows(const float* __restrict__ head, const float* __restrict__ dep,
                       const float* __restrict__ W,
                       float* __restrict__ hs, float* __restrict__ ds,
                       short* __restrict__ headB, short* __restrict__ depB) {
  const float* X; const float* wv; float* sv; short* XB;
  if (blockIdx.y == 0) { X = head; wv = W;      sv = hs; XB = headB; }
  else                 { X = dep;  wv = W + D_; sv = ds; XB = depB;  }
  const int row = blockIdx.x * 4 + (threadIdx.x >> 6);
  const int l = threadIdx.x & 63;
  const float4 v  = *(const float4*)(X + (size_t)row * D_ + l * 4);
  const float4 wq = *(const float4*)(wv + l * 4);
  short4v pk;
  pk[0] = bf16of(v.x); pk[1] = bf16of(v.y); pk[2] = bf16of(v.z); pk[3] = bf16of(v.w);
  *(short4v*)(XB + (size_t)row * D_ + l * 4) = pk;
  float p = v.x * wq.x + v.y * wq.y + v.z * wq.z + v.w * wq.w;
  p += __shfl_xor(p, 1); p += __shfl_xor(p, 2); p += __shfl_xor(p, 4);
  p += __shfl_xor(p, 8); p += __shfl_xor(p, 16); p += __shfl_xor(p, 32);
  if (l == 0) sv[row] = p;
}

// ------------- Fused K1+K2: per block = (batch b, 64-row i-stripe, 1024-col o-half) -------------
// 1-D grid of 512 with a DESIGNED XCD mapping: block n -> b=n&7, s=n>>3, oh=s>>5, ib=s&31.
// With round-robin wg->XCD (xcd = n%8), XCD x processes exactly batch b=x:
// its depB working set (512KB active half) + headB (1MB) + UT (128KB) stay L2-resident,
// so depB/headB are fetched from HBM once instead of up to 32x.
// Phase A: sAh[64 i][256 k] = bf16(headB[stripe] @ U), operands direct from L2.
// Phase B: 8 o-tiles x 4 k-slices; depB staged (double-buffered, counted vmcnt),
//   Ahat read from resident LDS. LDS 64 KB -> 2 blocks/CU.
__launch_bounds__(256, 2)
__global__ void k_fused(const short* __restrict__ headB, const short* __restrict__ UT,
                        const short* __restrict__ depB,
                        const float* __restrict__ hs, const float* __restrict__ ds,
                        const float* __restrict__ eb, float* __restrict__ out) {
  __shared__ __align__(16) short sAh[64 * 256];     // 32 KB: Ahat stripe, 32 slots/row, swizzled
  __shared__ __align__(16) short sD[2 * 128 * 64];  // 32 KB: depB slice double-buffer
  const int t = threadIdx.x;
  const int w = t >> 6;
  const int l = t & 63;
  const int quad = l >> 4;
  const int r15 = l & 15;
  const int sw = r15 & 7;
  const int n  = blockIdx.x;
  const int b  = n & 7;                  // XCD-pinned batch
  const int s_ = n >> 3;
  const int oh = s_ >> 5;                // 0..1  (o-half)
  const int ib = s_ & 31;                // 0..31 (i-stripe)
  const int irow0 = b * S_ + ib * 64;    // global flat row of i=0
  const int orow0 = b * S_ + oh * 1024;  // global flat row of o-half base
  const int ocol0 = oh * 1024;

  // early depB prefetch (slices 0,1 = o-tile 0, k 0/64) — overlaps phase A
  stage_tile64(depB + (size_t)orow0 * D_, (char*)sD, t, 0);
  stage_tile64(depB + (size_t)orow0 * D_, (char*)sD + 16384, t, 64);

  // ---------------- Phase A ----------------
  {
    f32x4 accA[4][4];
#pragma unroll
    for (int i = 0; i < 4; ++i)
#pragma unroll
      for (int j = 0; j < 4; ++j) accA[i][j] = (f32x4)0.0f;

    // A-operand: UT rows (m = n_col), wave w owns n_col [w*64, w*64+64)
    // B-operand: headB stripe rows (n = i), shared by all waves
    const short* pUg = UT + (size_t)(w * 64 + r15) * D_ + quad * 8;
    const short* pHg = headB + (size_t)(irow0 + r15) * D_ + quad * 8;
#pragma unroll 2
    for (int k0 = 0; k0 < D_; k0 += 32) {
      short8 aF[4], bF[4];
#pragma unroll
      for (int ar = 0; ar < 4; ++ar)
        aF[ar] = *(const short8*)(pUg + (size_t)(ar * 16) * D_ + k0);
#pragma unroll
      for (int nt = 0; nt < 4; ++nt)
        bF[nt] = *(const short8*)(pHg + (size_t)(nt * 16) * D_ + k0);
#pragma unroll
      for (int ar = 0; ar < 4; ++ar)
#pragma unroll
        for (int nt = 0; nt < 4; ++nt)
          accA[ar][nt] = __builtin_amdgcn_mfma_f32_16x16x32_bf16(aF[ar], bF[nt], accA[ar][nt], 0, 0, 0);
    }

    // write stripe to LDS: element (i, ncol); slot = ncol>>3, phys = low3 XOR (i&7)
#pragma unroll
    for (int ar = 0; ar < 4; ++ar) {
      const int ncol = w * 64 + ar * 16 + quad * 4;
      const int slot = ncol >> 3;
      const int half = (ncol >> 2) & 1;
#pragma unroll
      for (int nt = 0; nt < 4; ++nt) {
        const int i = nt * 16 + r15;
        const int sp = (slot & 24) | ((slot ^ i) & 7);
        short4v pk;
        pk[0] = bf16of(accA[ar][nt][0]); pk[1] = bf16of(accA[ar][nt][1]);
        pk[2] = bf16of(accA[ar][nt][2]); pk[3] = bf16of(accA[ar][nt][3]);
        *(short4v*)((char*)sAh + (size_t)i * 512 + sp * 16 + half * 8) = pk;
      }
    }
  }
  asm volatile("s_waitcnt lgkmcnt(0)" ::: "memory");
  __builtin_amdgcn_s_barrier();

  // ---------------- Phase B ----------------
  f32x4 acc[2][4];
#pragma unroll
  for (int i = 0; i < 2; ++i)
#pragma unroll
    for (int j = 0; j < 4; ++j) acc[i][j] = (f32x4)0.0f;

  const float bias = eb[0];
  float hv[4];
#pragma unroll
  for (int nt = 0; nt < 4; ++nt)
    hv[nt] = hs[irow0 + nt * 16 + r15] + bias;

  // slice s (0..31): o-tile = s>>2, k-slice = (s&3)*64
  for (int s = 0; s < 32; ++s) {
    if (s < 31) asm volatile("s_waitcnt vmcnt(4)" ::: "memory");
    else        asm volatile("s_waitcnt vmcnt(0)" ::: "memory");
    __builtin_amdgcn_s_barrier();

    const short8* pA = (const short8*)(sD + (size_t)(s & 1) * (128 * 64));
    const short8* pB = (const short8*)sAh;
#pragma unroll
    for (int ks = 0; ks < 2; ++ks) {
      const int soA = (ks * 4 + quad) ^ sw;            // slice-local slot (8/row)
      const int sgB = (s & 3) * 8 + ks * 4 + quad;     // global Ahat slot (32/row)
      const int soB = (sgB & 24) | ((sgB ^ r15) & 7);
      short8 aF[2], bF[4];
#pragma unroll
      for (int mt = 0; mt < 2; ++mt)   // A-operand: depB rows (m = o), wave w: o [w*32,+32)
        aF[mt] = pA[(w * 32 + mt * 16 + r15) * 8 + soA];
#pragma unroll
      for (int nt = 0; nt < 4; ++nt)   // B-operand: Ahat rows (n = i)
        bF[nt] = pB[(nt * 16 + r15) * 32 + soB];
#pragma unroll
      for (int mt = 0; mt < 2; ++mt)
#pragma unroll
        for (int nt = 0; nt < 4; ++nt)
          acc[mt][nt] = __builtin_amdgcn_mfma_f32_16x16x32_bf16(aF[mt], bF[nt], acc[mt][nt], 0, 0, 0);
    }
    __builtin_amdgcn_s_barrier();

    if (s < 30) {
      const int s2 = s + 2;
      stage_tile64(depB + (size_t)(orow0 + (s2 >> 2) * 128) * D_,
                   (char*)sD + (size_t)(s & 1) * 16384, t, (s2 & 3) * 64);
    }

    if ((s & 3) == 3) {  // o-tile complete: epilogue + acc reset
      const int ot = s >> 2;
#pragma unroll
      for (int mt = 0; mt < 2; ++mt) {
        const int o_loc = w * 32 + mt * 16 + quad * 4;
        f32x4 dsv = *(const f32x4*)(ds + orow0 + ot * 128 + o_loc);
#pragma unroll
        for (int nt = 0; nt < 4; ++nt) {
          const int i = nt * 16 + r15;
          f32x4 a = acc[mt][nt];
          f32x4 o4;
          o4[0] = a[0] + hv[nt] + dsv[0];
          o4[1] = a[1] + hv[nt] + dsv[1];
          o4[2] = a[2] + hv[nt] + dsv[2];
          o4[3] = a[3] + hv[nt] + dsv[3];
          *(f32x4*)(out + (size_t)(irow0 + i) * S_ + ocol0 + ot * 128 + o_loc) = o4;
          acc[mt][nt] = (f32x4)0.0f;
        }
      }
    }
  }
}

extern "C" void kernel_launch(void* const* d_in, const int* in_sizes, int n_in,
                              void* d_out, int out_size, void* d_ws, size_t ws_size,
                              hipStream_t stream) {
  const float* head = (const float*)d_in[0];
  const float* dep  = (const float*)d_in[1];
  const float* U    = (const float*)d_in[2];
  const float* W    = (const float*)d_in[3];  // (1, 512): wh | wd
  const float* eb   = (const float*)d_in[4];
  float* out = (float*)d_out;

  char* ws = (char*)d_ws;
  short* UT    = (short*)ws;                       // 256*256*2     = 128 KB
  float* hs    = (float*)(ws + (128 << 10));       // 16384*4       = 64 KB
  float* ds    = (float*)(ws + (192 << 10));       // 16384*4       = 64 KB
  short* headB = (short*)(ws + (256 << 10));       // 16384*256*2   = 8 MB
  short* depB  = (short*)(ws + (256 << 10) + (8 << 20));

  k_prep_u<<<dim3(256), dim3(256), 0, stream>>>(U, UT);
  k_rows<<<dim3(NROWS / 4, 2), dim3(256), 0, stream>>>(head, dep, W, hs, ds, headB, depB);
  k_fused<<<dim3(512), dim3(256), 0, stream>>>(headB, UT, depB, hs, ds, eb, out);
}

// Round 8
// 192.149 us; speedup vs baseline: 1.0423x; 1.0423x over previous
//
#include <hip/hip_runtime.h>
#include <hip/hip_bf16.h>
#include <stdint.h>
#include <stddef.h>

#define B_ 8
#define S_ 2048
#define D_ 256
#define NROWS (B_ * S_)  // 16384

typedef __attribute__((ext_vector_type(8))) short short8;
typedef __attribute__((ext_vector_type(4))) short short4v;
typedef __attribute__((ext_vector_type(4))) float f32x4;

// round-to-nearest-even fp32 -> bf16 bit pattern
__device__ __forceinline__ short bf16of(float f) {
  union { float f; unsigned u; } x; x.f = f;
  unsigned r = x.u + 0x7FFFu + ((x.u >> 16) & 1u);
  return (short)(r >> 16);
}

// async global->LDS, 16B per lane (wave-uniform base + lane*16 layout)
__device__ __forceinline__ void async_ld16(const void* g, void* s) {
  __builtin_amdgcn_global_load_lds(
      (const __attribute__((address_space(1))) void*)g,
      (__attribute__((address_space(3))) void*)s, 16, 0, 0);
}

// Stage one 128x64 bf16 tile (1024 16B-slots, 8 slots/row) into LDS.
// LINEAR LDS dest; swizzle via permuted GLOBAL source (rule #21):
//   physical slot sp at row r holds logical slot sl = sp ^ (r&7).
// 4 issues per thread.
__device__ __forceinline__ void stage_tile64(const short* __restrict__ g_row0,
                                             char* lds_base, int t, int kk0) {
#pragma unroll
  for (int c = 0; c < 4; ++c) {
    int p = c * 256 + t;
    int r = p >> 3;
    int sl = (p & 7) ^ (r & 7);
    async_ld16(g_row0 + (size_t)r * D_ + kk0 + sl * 8, lds_base + p * 16);
  }
}

// ---- K_rows (merged with U-prep): one launch does
//   bx in [0,4096):     head rows  -> hs, headB
//   bx in [4096,8192):  dep rows   -> ds, depB
//   bx in [8192,8448):  UT[n][k] = bf16(U[k][n])   (n = bx-8192)
__global__ void k_rows(const float* __restrict__ head, const float* __restrict__ dep,
                       const float* __restrict__ U, const float* __restrict__ W,
                       float* __restrict__ hs, float* __restrict__ ds,
                       short* __restrict__ headB, short* __restrict__ depB,
                       short* __restrict__ UT) {
  const int bx = blockIdx.x;
  if (bx >= 8192) {  // U transpose (256 KB total; uniform per-block branch)
    const int n = bx - 8192;
    const int k = threadIdx.x;
    UT[n * D_ + k] = bf16of(U[k * D_ + n]);
    return;
  }
  const float* X; const float* wv; float* sv; short* XB; int rbase;
  if (bx < 4096) { X = head; wv = W;      sv = hs; XB = headB; rbase = bx * 4; }
  else           { X = dep;  wv = W + D_; sv = ds; XB = depB;  rbase = (bx - 4096) * 4; }
  const int row = rbase + (threadIdx.x >> 6);
  const int l = threadIdx.x & 63;
  const float4 v  = *(const float4*)(X + (size_t)row * D_ + l * 4);
  const float4 wq = *(const float4*)(wv + l * 4);
  short4v pk;
  pk[0] = bf16of(v.x); pk[1] = bf16of(v.y); pk[2] = bf16of(v.z); pk[3] = bf16of(v.w);
  *(short4v*)(XB + (size_t)row * D_ + l * 4) = pk;
  float p = v.x * wq.x + v.y * wq.y + v.z * wq.z + v.w * wq.w;
  p += __shfl_xor(p, 1); p += __shfl_xor(p, 2); p += __shfl_xor(p, 4);
  p += __shfl_xor(p, 8); p += __shfl_xor(p, 16); p += __shfl_xor(p, 32);
  if (l == 0) sv[row] = p;
}

// ---------------- K1: Ahat = headB @ U (bf16) ----------------
// Staged, swizzled LDS, counted-vmcnt double buffer. BK=64, 4 K-steps.
// A-operand = UT rows (m = n_col), B-operand = headB rows (n = i).
__launch_bounds__(256, 2)
__global__ void k_ahat(const short* __restrict__ headB, const short* __restrict__ UT,
                       short* __restrict__ Ahat) {
  __shared__ __align__(16) short sU[2 * 128 * 64];  // 32 KB (2 buffers)
  __shared__ __align__(16) short sH[2 * 128 * 64];  // 32 KB
  const int t = threadIdx.x;
  const int w = t >> 6;
  const int l = t & 63;
  const int quad = l >> 4;
  const int r15 = l & 15;
  const int sw = r15 & 7;                // read-side slot swizzle
  const int nbase = blockIdx.x * 128;
  const int mbase = blockIdx.y * 128;

  const short* gA = UT + (size_t)nbase * D_;
  const short* gB = headB + (size_t)mbase * D_;

  f32x4 acc[4][4];
#pragma unroll
  for (int i = 0; i < 4; ++i)
#pragma unroll
    for (int j = 0; j < 4; ++j) acc[i][j] = (f32x4)0.0f;

  // prologue: fill both buffers (8 issues per wave per buffer)
  stage_tile64(gA, (char*)sU, t, 0);
  stage_tile64(gB, (char*)sH, t, 0);
  stage_tile64(gA, (char*)sU + 16384, t, 64);
  stage_tile64(gB, (char*)sH + 16384, t, 64);

  const int baseA = ((w >> 1) * 64 + r15) * 8;
  const int baseB = ((w & 1) * 64 + r15) * 8;

#pragma unroll
  for (int it = 0; it < 4; ++it) {
    if (it < 3) asm volatile("s_waitcnt vmcnt(8)" ::: "memory");
    else        asm volatile("s_waitcnt vmcnt(0)" ::: "memory");
    __builtin_amdgcn_s_barrier();

    const short8* pA = (const short8*)(sU + (size_t)(it & 1) * (128 * 64));
    const short8* pB = (const short8*)(sH + (size_t)(it & 1) * (128 * 64));
#pragma unroll
    for (int kb = 0; kb < 2; ++kb) {
      const int so = (kb * 4 + quad) ^ sw;
      short8 aF[4], bF[4];
#pragma unroll
      for (int mt = 0; mt < 4; ++mt) aF[mt] = pA[baseA + mt * 128 + so];
#pragma unroll
      for (int nt = 0; nt < 4; ++nt) bF[nt] = pB[baseB + nt * 128 + so];
#pragma unroll
      for (int mt = 0; mt < 4; ++mt)
#pragma unroll
        for (int nt = 0; nt < 4; ++nt)
          acc[mt][nt] = __builtin_amdgcn_mfma_f32_16x16x32_bf16(aF[mt], bF[nt], acc[mt][nt], 0, 0, 0);
    }
    __builtin_amdgcn_s_barrier();      // all waves done reading buf[it&1]
    if (it < 2) {                      // refill the buffer just consumed
      stage_tile64(gA, (char*)sU + (size_t)(it & 1) * 16384, t, (it + 2) * 64);
      stage_tile64(gB, (char*)sH + (size_t)(it & 1) * 16384, t, (it + 2) * 64);
    }
  }

  // D[m=n_col][n=i] -> lane holds 4 consecutive n_col for fixed i: short4 stores
#pragma unroll
  for (int mt = 0; mt < 4; ++mt) {
    int n_loc = (w >> 1) * 64 + mt * 16 + quad * 4;
#pragma unroll
    for (int nt = 0; nt < 4; ++nt) {
      int i_loc = (w & 1) * 64 + nt * 16 + r15;
      short4v pk;
      pk[0] = bf16of(acc[mt][nt][0]); pk[1] = bf16of(acc[mt][nt][1]);
      pk[2] = bf16of(acc[mt][nt][2]); pk[3] = bf16of(acc[mt][nt][3]);
      *(short4v*)(Ahat + (size_t)(mbase + i_loc) * D_ + nbase + n_loc) = pk;
    }
  }
}

// ------- K2: out[b,i,o] = sum_k Ahat[b,i,k] depB[b,o,k] + hs[i] + ds[o] + bias -------
// grid (16 o-tiles, 16 i-tiles, 8 b); A-operand = depB (m = o), B-operand = Ahat (n = i)
// Staged, swizzled LDS, counted-vmcnt double buffer. BK=64, 4 K-steps.
__launch_bounds__(256, 2)
__global__ void k_main(const short* __restrict__ Ahat, const short* __restrict__ depB,
                       const float* __restrict__ hs, const float* __restrict__ ds,
                       const float* __restrict__ eb, float* __restrict__ out) {
  __shared__ __align__(16) short sD[2 * 128 * 64];   // 32 KB: depB rows (o)
  __shared__ __align__(16) short sAh[2 * 128 * 64];  // 32 KB: Ahat rows (i)
  const int t = threadIdx.x;
  const int w = t >> 6;
  const int l = t & 63;
  const int quad = l >> 4;
  const int r15 = l & 15;
  const int sw = r15 & 7;
  const int b = blockIdx.z;
  const int mbase = blockIdx.y * 128;  // i
  const int nbase = blockIdx.x * 128;  // o

  const short* gA = depB + (size_t)(b * S_ + nbase) * D_;
  const short* gB = Ahat + (size_t)(b * S_ + mbase) * D_;

  f32x4 acc[4][4];
#pragma unroll
  for (int i = 0; i < 4; ++i)
#pragma unroll
    for (int j = 0; j < 4; ++j) acc[i][j] = (f32x4)0.0f;

  stage_tile64(gA, (char*)sD, t, 0);
  stage_tile64(gB, (char*)sAh, t, 0);
  stage_tile64(gA, (char*)sD + 16384, t, 64);
  stage_tile64(gB, (char*)sAh + 16384, t, 64);

  const int baseA = ((w >> 1) * 64 + r15) * 8;
  const int baseB = ((w & 1) * 64 + r15) * 8;

#pragma unroll
  for (int it = 0; it < 4; ++it) {
    if (it < 3) asm volatile("s_waitcnt vmcnt(8)" ::: "memory");
    else        asm volatile("s_waitcnt vmcnt(0)" ::: "memory");
    __builtin_amdgcn_s_barrier();

    const short8* pA = (const short8*)(sD + (size_t)(it & 1) * (128 * 64));
    const short8* pB = (const short8*)(sAh + (size_t)(it & 1) * (128 * 64));
#pragma unroll
    for (int kb = 0; kb < 2; ++kb) {
      const int so = (kb * 4 + quad) ^ sw;
      short8 aF[4], bF[4];
#pragma unroll
      for (int mt = 0; mt < 4; ++mt) aF[mt] = pA[baseA + mt * 128 + so];
#pragma unroll
      for (int nt = 0; nt < 4; ++nt) bF[nt] = pB[baseB + nt * 128 + so];
#pragma unroll
      for (int mt = 0; mt < 4; ++mt)
#pragma unroll
        for (int nt = 0; nt < 4; ++nt)
          acc[mt][nt] = __builtin_amdgcn_mfma_f32_16x16x32_bf16(aF[mt], bF[nt], acc[mt][nt], 0, 0, 0);
    }
    __builtin_amdgcn_s_barrier();
    if (it < 2) {
      stage_tile64(gA, (char*)sD + (size_t)(it & 1) * 16384, t, (it + 2) * 64);
      stage_tile64(gB, (char*)sAh + (size_t)(it & 1) * 16384, t, (it + 2) * 64);
    }
  }

  const float bias = eb[0];
  float hv4[4];
#pragma unroll
  for (int nt = 0; nt < 4; ++nt)
    hv4[nt] = hs[(size_t)b * S_ + mbase + (w & 1) * 64 + nt * 16 + r15] + bias;

#pragma unroll
  for (int mt = 0; mt < 4; ++mt) {
    int o_loc = (w >> 1) * 64 + mt * 16 + quad * 4;
    f32x4 dsv = *(const f32x4*)(ds + (size_t)b * S_ + nbase + o_loc);
#pragma unroll
    for (int nt = 0; nt < 4; ++nt) {
      int i_loc = (w & 1) * 64 + nt * 16 + r15;
      float hv = hv4[nt];
      f32x4 a = acc[mt][nt];
      f32x4 o4;
      o4[0] = a[0] + hv + dsv[0];
      o4[1] = a[1] + hv + dsv[1];
      o4[2] = a[2] + hv + dsv[2];
      o4[3] = a[3] + hv + dsv[3];
      *(f32x4*)(out + (size_t)(b * S_ + mbase + i_loc) * S_ + nbase + o_loc) = o4;
    }
  }
}

extern "C" void kernel_launch(void* const* d_in, const int* in_sizes, int n_in,
                              void* d_out, int out_size, void* d_ws, size_t ws_size,
                              hipStream_t stream) {
  const float* head = (const float*)d_in[0];
  const float* dep  = (const float*)d_in[1];
  const float* U    = (const float*)d_in[2];
  const float* W    = (const float*)d_in[3];  // (1, 512): wh | wd
  const float* eb   = (const float*)d_in[4];
  float* out = (float*)d_out;

  char* ws = (char*)d_ws;
  short* UT    = (short*)ws;                       // 256*256*2     = 128 KB
  float* hs    = (float*)(ws + (128 << 10));       // 16384*4       = 64 KB
  float* ds    = (float*)(ws + (192 << 10));       // 16384*4       = 64 KB
  short* headB = (short*)(ws + (256 << 10));       // 16384*256*2   = 8 MB
  short* depB  = (short*)(ws + (256 << 10) + (8 << 20));
  short* Ahat  = (short*)(ws + (256 << 10) + (16 << 20));

  k_rows<<<dim3(8448), dim3(256), 0, stream>>>(head, dep, U, W, hs, ds, headB, depB, UT);
  k_ahat<<<dim3(2, 128), dim3(256), 0, stream>>>(headB, UT, Ahat);
  k_main<<<dim3(16, 16, 8), dim3(256), 0, stream>>>(Ahat, depB, hs, ds, eb, out);
}